// Round 14
// baseline (198.179 us; speedup 1.0000x reference)
//
#include <hip/hip_runtime.h>
#include <cstdint>
#include <math.h>

typedef unsigned short ushort_t;
typedef unsigned int uint_t;
typedef __bf16 v8bf __attribute__((ext_vector_type(8)));
typedef float v16f __attribute__((ext_vector_type(16)));

constexpr int B_SZ = 32, NQ = 2048, NK = 2048, DH = 128;
constexpr int BQ2 = 128, BK = 64;   // 128 q-rows/block = 4 waves x 32 rows
constexpr int NQT = NQ / BQ2;       // 16 q-tiles per batch
// Q prescaled by SCALE*log2e so softmax uses raw v_exp_f32 (2^x), no mul:
// p = 2^(s' - M2), s' = score*log2e, M2 = M_FIX*log2e. Fixed-shift softmax
// (rounds 3-13 verified): partials over disjoint keys ADD.
constexpr float QSCALE = 0.12751880226116815f;   // (1/sqrt(128)) * log2(e)
constexpr float M2 = 17.312340490667561f;        // 12 * log2(e)

// 16B-chunk XOR swizzles (bank-uniform for all patterns below).
__device__ inline int swzK(int row, int chunk) {  // K: [64][128] bf16, chunk=col>>3
  return row * 128 + ((chunk ^ (row & 7)) << 3);
}
__device__ inline int swzV(int d, int chunk) {  // Vt: [128][64] bf16, chunk=k>>3
  return d * 64 + ((chunk ^ (d & 7)) << 3);
}

__device__ __forceinline__ float4 ld4f(const float* p) {
  return *reinterpret_cast<const float4*>(p);
}
__device__ __forceinline__ uint4 ld4u(const ushort_t* p) {
  return *reinterpret_cast<const uint4*>(p);
}

__device__ inline v8bf cvt8(const float* __restrict__ p) {
  float4 f0 = ld4f(p);
  float4 f1 = ld4f(p + 4);
  v8bf r;
  r[0] = (__bf16)f0.x; r[1] = (__bf16)f0.y; r[2] = (__bf16)f0.z; r[3] = (__bf16)f0.w;
  r[4] = (__bf16)f1.x; r[5] = (__bf16)f1.y; r[6] = (__bf16)f1.z; r[7] = (__bf16)f1.w;
  return r;
}

__device__ inline v8bf cvt8s(const float* __restrict__ p, float s) {  // scaled (Q)
  float4 f0 = ld4f(p);
  float4 f1 = ld4f(p + 4);
  v8bf r;
  r[0] = (__bf16)(f0.x * s); r[1] = (__bf16)(f0.y * s);
  r[2] = (__bf16)(f0.z * s); r[3] = (__bf16)(f0.w * s);
  r[4] = (__bf16)(f1.x * s); r[5] = (__bf16)(f1.y * s);
  r[6] = (__bf16)(f1.z * s); r[7] = (__bf16)(f1.w * s);
  return r;
}

__device__ inline v8bf cvt8r(const float4 f0, const float4 f1) {
  v8bf r;
  r[0] = (__bf16)f0.x; r[1] = (__bf16)f0.y; r[2] = (__bf16)f0.z; r[3] = (__bf16)f0.w;
  r[4] = (__bf16)f1.x; r[5] = (__bf16)f1.y; r[6] = (__bf16)f1.z; r[7] = (__bf16)f1.w;
  return r;
}

__device__ __forceinline__ uint_t pk2(float a, float b) {  // 2 f32 -> packed 2x bf16
  const ushort_t ua = __builtin_bit_cast(ushort_t, (__bf16)a);
  const ushort_t ub = __builtin_bit_cast(ushort_t, (__bf16)b);
  return (uint_t)ua | ((uint_t)ub << 16);
}

// ---------------- V prepass: Vt[b][d][k] = bf16(V[b][k][d]) -------------------
__global__ __launch_bounds__(256) void transpose_v(const float* __restrict__ V,
                                                   ushort_t* __restrict__ Vt) {
  __shared__ __align__(16) ushort_t st[64 * 128];
  const int b = blockIdx.y, k0 = blockIdx.x * 64, t = threadIdx.x;
  for (int c = 0; c < 4; ++c) {
    const int row = (t >> 4) + 16 * c;
    const int col = (t & 15) * 8;
    v8bf v = cvt8(V + ((size_t)(b * NK + k0 + row)) * DH + col);
    const int chunk = (col >> 3) ^ ((row >> 3) & 7);
    *reinterpret_cast<v8bf*>(&st[row * 128 + chunk * 8]) = v;
  }
  __syncthreads();
  for (int c = 0; c < 4; ++c) {
    const int d = (t >> 3) + 32 * c;
    const int kc = (t & 7) * 8;
    alignas(16) ushort_t tmp[8];
    for (int j = 0; j < 8; ++j) {
      const int row = kc + j;
      const int elem = (d & 7) | (((d >> 3) ^ ((row >> 3) & 7)) << 3);
      tmp[j] = st[row * 128 + elem];
    }
    *reinterpret_cast<uint4*>(Vt + ((size_t)(b * DH + d)) * NK + k0 + kc) =
        *reinterpret_cast<const uint4*>(tmp);
  }
}

// QK^T half-tiles + fixed-shift softmax + in-register P-frag build (both kb).
// Produces the 4 PV A-frags for tile at key-offset k0n. Layouts verified r11.
__device__ __forceinline__ void qk_sm(const ushort_t* sk, int l32, int hi, int k0n,
                                      int valid, const v8bf* qf, float& ls0,
                                      float& ls1, uint4& pa0, uint4& pa1,
                                      uint4& pa2, uint4& pa3) {
  const bool part = (k0n + BK > valid);
#pragma unroll
  for (int kb = 0; kb < 2; ++kb) {
    const int rowA = kb * 32 + l32;
    const uint4 kf0 = ld4u(&sk[swzK(rowA, 0 + hi)]);
    const uint4 kf1 = ld4u(&sk[swzK(rowA, 2 + hi)]);
    const uint4 kf2 = ld4u(&sk[swzK(rowA, 4 + hi)]);
    const uint4 kf3 = ld4u(&sk[swzK(rowA, 6 + hi)]);
    const uint4 kf4 = ld4u(&sk[swzK(rowA, 8 + hi)]);
    const uint4 kf5 = ld4u(&sk[swzK(rowA, 10 + hi)]);
    const uint4 kf6 = ld4u(&sk[swzK(rowA, 12 + hi)]);
    const uint4 kf7 = ld4u(&sk[swzK(rowA, 14 + hi)]);
    v16f sa;
#pragma unroll
    for (int r = 0; r < 16; ++r) sa[r] = 0.f;
    __builtin_amdgcn_s_setprio(1);
    sa = __builtin_amdgcn_mfma_f32_32x32x16_bf16(__builtin_bit_cast(v8bf, kf0), qf[0], sa, 0, 0, 0);
    sa = __builtin_amdgcn_mfma_f32_32x32x16_bf16(__builtin_bit_cast(v8bf, kf1), qf[1], sa, 0, 0, 0);
    sa = __builtin_amdgcn_mfma_f32_32x32x16_bf16(__builtin_bit_cast(v8bf, kf2), qf[2], sa, 0, 0, 0);
    sa = __builtin_amdgcn_mfma_f32_32x32x16_bf16(__builtin_bit_cast(v8bf, kf3), qf[3], sa, 0, 0, 0);
    sa = __builtin_amdgcn_mfma_f32_32x32x16_bf16(__builtin_bit_cast(v8bf, kf4), qf[4], sa, 0, 0, 0);
    sa = __builtin_amdgcn_mfma_f32_32x32x16_bf16(__builtin_bit_cast(v8bf, kf5), qf[5], sa, 0, 0, 0);
    sa = __builtin_amdgcn_mfma_f32_32x32x16_bf16(__builtin_bit_cast(v8bf, kf6), qf[6], sa, 0, 0, 0);
    sa = __builtin_amdgcn_mfma_f32_32x32x16_bf16(__builtin_bit_cast(v8bf, kf7), qf[7], sa, 0, 0, 0);
    __builtin_amdgcn_s_setprio(0);
    // mask + p = 2^(s' - M2); C row = (r&3)+8*(r>>2)+4*hi  [m74/m101]
    float p[16];
#pragma unroll
    for (int r = 0; r < 16; ++r) {
      const int crow = (r & 3) + 8 * (r >> 2) + 4 * hi;
      float x = sa[r];
      if (part) x = (k0n + kb * 32 + crow < valid) ? x : -1e30f;
      float e;
      asm("v_exp_f32 %0, %1" : "=v"(e) : "v"(x - M2));  // 2^arg; -1e30 -> 0
      p[r] = e;
      if (r < 8) ls0 += e; else ls1 += e;
    }
    // P -> PV A-frags; swap(A,B) = hi-lanes' A <-> lo-lanes' B (r11-verified)
#pragma unroll
    for (int q2 = 0; q2 < 2; ++q2) {
      uint_t A0 = pk2(p[8 * q2 + 0], p[8 * q2 + 1]);
      uint_t A1 = pk2(p[8 * q2 + 2], p[8 * q2 + 3]);
      uint_t B0 = pk2(p[8 * q2 + 4], p[8 * q2 + 5]);
      uint_t B1 = pk2(p[8 * q2 + 6], p[8 * q2 + 7]);
      asm("v_permlane32_swap_b32 %0, %1" : "+v"(A0), "+v"(B0));
      asm("v_permlane32_swap_b32 %0, %1" : "+v"(A1), "+v"(B1));
      uint4 fw;
      fw.x = A0; fw.y = A1; fw.z = B0; fw.w = B1;
      if (kb == 0) { if (q2 == 0) pa0 = fw; else pa1 = fw; }
      else         { if (q2 == 0) pa2 = fw; else pa3 = fw; }
    }
  }
}

// One PV quarter: O += P[:,16ksg..16ksg+15] x V[16ksg..,:]
__device__ __forceinline__ void pv4(const ushort_t* sv, int l32, int hi,
                                    const uint4 paf, int ksg, v16f* o) {
  const uint4 vf0 = ld4u(&sv[swzV(0 + l32, 2 * ksg + hi)]);
  const uint4 vf1 = ld4u(&sv[swzV(32 + l32, 2 * ksg + hi)]);
  const uint4 vf2 = ld4u(&sv[swzV(64 + l32, 2 * ksg + hi)]);
  const uint4 vf3 = ld4u(&sv[swzV(96 + l32, 2 * ksg + hi)]);
  const v8bf pa = __builtin_bit_cast(v8bf, paf);
  __builtin_amdgcn_s_setprio(1);
  o[0] = __builtin_amdgcn_mfma_f32_32x32x16_bf16(pa, __builtin_bit_cast(v8bf, vf0), o[0], 0, 0, 0);
  o[1] = __builtin_amdgcn_mfma_f32_32x32x16_bf16(pa, __builtin_bit_cast(v8bf, vf1), o[1], 0, 0, 0);
  o[2] = __builtin_amdgcn_mfma_f32_32x32x16_bf16(pa, __builtin_bit_cast(v8bf, vf2), o[2], 0, 0, 0);
  o[3] = __builtin_amdgcn_mfma_f32_32x32x16_bf16(pa, __builtin_bit_cast(v8bf, vf3), o[3], 0, 0, 0);
  __builtin_amdgcn_s_setprio(0);
}

// ---------------- Flash attention: 2-barrier software pipeline -----------------
// Per iter t: stage(t+1) -> B1 -> [ PV(t) from buf[t&1]  ||  QK(t+1)+softmax
// from buf[(t+1)&1], rebuilding P-frags ] -> B2. The two streams are
// independent -> compiler interleaves MFMA/ds_read/VALU across them, cutting
// the solo-wave critical path (wall ~= heaviest nt=32 block running alone).
// Buffer safety: writes at iter t hit buf[(t+1)&1], last read by PV(t-1)
// before B2(t-1); QK(t+1) reads after B1. 1 extra barrier vs r13, big overlap.
__global__ __launch_bounds__(256, 2) void attn(const float* __restrict__ Q,
                                               const float* __restrict__ K,
                                               const ushort_t* __restrict__ Vt,
                                               const int* __restrict__ vsl,
                                               float* __restrict__ Out) {
  __shared__ __align__(16) ushort_t sK2[2][64 * 128];  // bf16 K[key][d], swizzled
  __shared__ __align__(16) ushort_t sV2[2][DH * 64];   // bf16 Vt[d][key], swizzled

  const int t = threadIdx.x;
  const int lane = t & 63, w = t >> 6, hi = lane >> 5, l32 = lane & 31;

  // ---- in-kernel LPT scheduler (sort scratch overlays sK2) ----
  int* s_ord = reinterpret_cast<int*>(sK2);
  if (t < 32) {
    const int cx = (vsl[t] + 63) >> 6;
    int rank = 0;
    for (int y = 0; y < 32; ++y) {
      const int cy = (vsl[y] + 63) >> 6;
      rank += (cy > cx) || (cy == cx && y < t);
    }
    s_ord[rank] = t;
  }
  __syncthreads();
  const int n = (int)blockIdx.x;
  const int ci = n & 255, cj = n >> 8;
  const int ru = cj ? 511 - ci : ci;   // heavy+light co-CU: heavy runs uncontended
  const int b = s_ord[ru >> 4];
  const int qt2 = ru & 15;
  __syncthreads();  // s_ord consumed before staging overwrites sK2

  const int q0 = qt2 * BQ2;
  const int valid = vsl[b];
  const int nt = (valid + BK - 1) / BK;

  // Q regs (prescaled by QSCALE): B-frag ks: lane holds Q[q=l32][d=ks*16+hi*8+j]
  v8bf qf[8];
  {
    const float* qp = Q + ((size_t)(b * NQ + q0 + w * 32 + l32)) * DH + hi * 8;
#pragma unroll
    for (int ks = 0; ks < 8; ++ks) qf[ks] = cvt8s(qp + ks * 16, QSCALE);
  }

  v16f o[4];
#pragma unroll
  for (int nb = 0; nb < 4; ++nb)
#pragma unroll
    for (int r = 0; r < 16; ++r) o[nb][r] = 0.f;
  float ls0 = 0.f, ls1 = 0.f;  // split accumulators (halved dep chain)

  const float* Kb = K + (size_t)b * NK * DH;
  const ushort_t* Vb = Vt + (size_t)b * DH * NK;
  const int krow = t >> 4, kch = t & 15;  // K staging: rows krow+16c, chunk kch
  const int vd = t >> 3, vch = t & 7;     // V staging: d vd+32c, chunk vch

  // prefetch registers: named scalars only (rule #20 — no arrays)
  float4 k0a, k0b, k1a, k1b, k2a, k2b, k3a, k3b;
  uint4 v0r, v1r, v2r, v3r;

#define PREFETCH(KOFF)                                                   \
  do {                                                                   \
    const float* p0_ = Kb + (size_t)((KOFF) + krow) * DH + kch * 8;      \
    const float* p1_ = Kb + (size_t)((KOFF) + krow + 16) * DH + kch * 8; \
    const float* p2_ = Kb + (size_t)((KOFF) + krow + 32) * DH + kch * 8; \
    const float* p3_ = Kb + (size_t)((KOFF) + krow + 48) * DH + kch * 8; \
    k0a = ld4f(p0_); k0b = ld4f(p0_ + 4);                                \
    k1a = ld4f(p1_); k1b = ld4f(p1_ + 4);                                \
    k2a = ld4f(p2_); k2b = ld4f(p2_ + 4);                                \
    k3a = ld4f(p3_); k3b = ld4f(p3_ + 4);                                \
    const ushort_t* q0_ = Vb + (size_t)(vd)*NK + (KOFF) + vch * 8;       \
    const ushort_t* q1_ = Vb + (size_t)(vd + 32) * NK + (KOFF) + vch * 8;\
    const ushort_t* q2_ = Vb + (size_t)(vd + 64) * NK + (KOFF) + vch * 8;\
    const ushort_t* q3_ = Vb + (size_t)(vd + 96) * NK + (KOFF) + vch * 8;\
    v0r = ld4u(q0_); v1r = ld4u(q1_); v2r = ld4u(q2_); v3r = ld4u(q3_);  \
  } while (0)

#define STAGE(SK_, SV_)                                                      \
  do {                                                                       \
    *reinterpret_cast<v8bf*>(&(SK_)[swzK(krow + 0, kch)]) = cvt8r(k0a, k0b); \
    *reinterpret_cast<v8bf*>(&(SK_)[swzK(krow + 16, kch)]) = cvt8r(k1a, k1b);\
    *reinterpret_cast<v8bf*>(&(SK_)[swzK(krow + 32, kch)]) = cvt8r(k2a, k2b);\
    *reinterpret_cast<v8bf*>(&(SK_)[swzK(krow + 48, kch)]) = cvt8r(k3a, k3b);\
    *reinterpret_cast<uint4*>(&(SV_)[swzV(vd + 0, vch)]) = v0r;              \
    *reinterpret_cast<uint4*>(&(SV_)[swzV(vd + 32, vch)]) = v1r;             \
    *reinterpret_cast<uint4*>(&(SV_)[swzV(vd + 64, vch)]) = v2r;             \
    *reinterpret_cast<uint4*>(&(SV_)[swzV(vd + 96, vch)]) = v3r;             \
  } while (0)

  // ---- prologue: tile 0 staged + QK(0)+softmax -> pa frags ----
  PREFETCH(0);
  STAGE(sK2[0], sV2[0]);
  if (nt > 1) PREFETCH(BK);
  __syncthreads();
  uint4 pa0, pa1, pa2, pa3;
  qk_sm(sK2[0], l32, hi, 0, valid, qf, ls0, ls1, pa0, pa1, pa2, pa3);

  for (int tile = 0; tile < nt; ++tile) {
    const int cur = tile & 1;
    if (tile + 1 < nt) {
      STAGE(sK2[cur ^ 1], sV2[cur ^ 1]);
      if (tile + 2 < nt) PREFETCH((tile + 2) * BK);
    }
    __syncthreads();  // B1: stage(t+1) visible; prior reads protected by B2(t-1)
    // PV(t) and QK(t+1) are independent: compiler interleaves the streams
    pv4(sV2[cur], l32, hi, pa0, 0, o);
    pv4(sV2[cur], l32, hi, pa1, 1, o);
    pv4(sV2[cur], l32, hi, pa2, 2, o);
    pv4(sV2[cur], l32, hi, pa3, 3, o);
    if (tile + 1 < nt)
      qk_sm(sK2[cur ^ 1], l32, hi, (tile + 1) * BK, valid, qf, ls0, ls1, pa0, pa1,
            pa2, pa3);
    __syncthreads();  // B2: all reads done -> next iter may overwrite buf[cur]
  }

  // ---- epilogue: row-sum = local + partner half; normalize + store ----
  const float lsum = ls0 + ls1;
  const float rs = lsum + __shfl_xor(lsum, 32);
  const float inv_own = 1.0f / rs;  // inv for q-row l32
#pragma unroll
  for (int r = 0; r < 16; ++r) {
    const int crow = (r & 3) + 8 * (r >> 2) + 4 * hi;  // O row = q-row crow
    const float inv = __shfl(inv_own, crow);           // lane crow holds its inv
    float* op = Out + ((size_t)(b * NQ + q0 + w * 32 + crow)) * DH + l32;
#pragma unroll
    for (int nb = 0; nb < 4; ++nb) op[nb * 32] = o[nb][r] * inv;
  }
#undef PREFETCH
#undef STAGE
}

extern "C" void kernel_launch(void* const* d_in, const int* in_sizes, int n_in,
                              void* d_out, int out_size, void* d_ws, size_t ws_size,
                              hipStream_t stream) {
  const float* Q = (const float*)d_in[0];
  const float* K = (const float*)d_in[1];
  const float* V = (const float*)d_in[2];
  const int* vsl = (const int*)d_in[3];
  float* Out = (float*)d_out;
  ushort_t* Vt = (ushort_t*)d_ws;  // 32*128*2048*2 = 16 MiB bf16 scratch

  transpose_v<<<dim3(NK / 64, B_SZ), dim3(256), 0, stream>>>(V, Vt);
  attn<<<dim3(B_SZ * NQT), dim3(256), 0, stream>>>(Q, K, Vt, vsl, Out);
}